// Round 7
// baseline (2696.625 us; speedup 1.0000x reference)
//
#include <hip/hip_runtime.h>
#include <math.h>

// ---------------- problem dims ----------------
#define E_DIM 512     // embedding dim
#define H_DIM 2048    // hidden
#define G_DIM 8192    // 4*H
#define B_DIM 32      // batch
#define T_DIM 128     // target time
#define S_DIM 128     // source time
#define ENC2  1024    // 2*encoder_hidden
#define SI_DIM 1536   // E + 2*enc (static input)

#define NBLK 256      // persistent blocks (1 per CU)
#define NTHR 512      // 8 waves
#define JT   8        // hidden cols per block
#define KHW  (H_DIM/8)   // 256: W_hh K-slice per wave
#define KXW  (E_DIM/8)   // 64:  W_ih K-slice per wave
#define HB   (B_DIM*H_DIM)   // 65536 elements per h buffer (u32 packed)

// ---------------- workspace layout (bytes) ----------------
// x_hi  bf16 [4096][512]  @ 0        (4194304)
// x_lo  bf16 [4096][512]  @ 4194304  (4194304)
// hp    u32  2x[32][2048] @ 8388608  (524288)   packed h: hi | lo<<16
// si    f32  [32][1536]   @ 8912896  (196608)
// flags u32  [256]x16     @ 9109504  (16384)    64B-strided arrival flags
// total ~9.1 MB

typedef __bf16 bf16_t;
typedef bf16_t bf16x8 __attribute__((ext_vector_type(8)));
typedef float f32x4 __attribute__((ext_vector_type(4)));
typedef unsigned int u32x4 __attribute__((ext_vector_type(4)));

__device__ __forceinline__ unsigned short f2bf(float x) {
    unsigned u = __float_as_uint(x);
    u += 0x7FFFu + ((u >> 16) & 1u);   // RNE
    return (unsigned short)(u >> 16);
}
__device__ __forceinline__ float bf2f(unsigned short s) {
    return __uint_as_float(((unsigned)s) << 16);
}
__device__ __forceinline__ unsigned pack2(float a, float b) {
    return (unsigned)f2bf(a) | ((unsigned)f2bf(b) << 16);
}
__device__ __forceinline__ f32x4 mfma16(bf16x8 a, bf16x8 b, f32x4 c) {
    return __builtin_amdgcn_mfma_f32_16x16x32_bf16(a, b, c, 0, 0, 0);
}
__device__ __forceinline__ bf16x8 tofrag(u32x4 q) {
    return __builtin_bit_cast(bf16x8, q);
}
__device__ __forceinline__ float sigf(float x) { return 1.f / (1.f + expf(-x)); }

// defeat rematerialization: value becomes asm-defined, compiler must keep it
#define OPAQUE(v) asm volatile("" : "+v"(v))

// x fragment load (ordinary cached loads; x is read-only)
__device__ __forceinline__ bf16x8 load_frag(const unsigned short* base) {
    const uint2* p = (const uint2*)base;
    uint2 a = p[0], b = p[4];
    uint4 q; q.x = a.x; q.y = a.y; q.z = b.x; q.w = b.y;
    return __builtin_bit_cast(bf16x8, q);
}

// h fragment pair load from PACKED u32 buffer via agent-scope bypass loads
__device__ __forceinline__ void lda_pair(const unsigned int* p, bf16x8& Ah, bf16x8& Al) {
    unsigned long long q0 = __hip_atomic_load((const unsigned long long*)(p),
                                              __ATOMIC_RELAXED, __HIP_MEMORY_SCOPE_AGENT);
    unsigned long long q1 = __hip_atomic_load((const unsigned long long*)(p + 2),
                                              __ATOMIC_RELAXED, __HIP_MEMORY_SCOPE_AGENT);
    unsigned long long q2 = __hip_atomic_load((const unsigned long long*)(p + 16),
                                              __ATOMIC_RELAXED, __HIP_MEMORY_SCOPE_AGENT);
    unsigned long long q3 = __hip_atomic_load((const unsigned long long*)(p + 18),
                                              __ATOMIC_RELAXED, __HIP_MEMORY_SCOPE_AGENT);
    unsigned p0 = (unsigned)q0, p1 = (unsigned)(q0 >> 32);
    unsigned p2 = (unsigned)q1, p3 = (unsigned)(q1 >> 32);
    unsigned p4 = (unsigned)q2, p5 = (unsigned)(q2 >> 32);
    unsigned p6 = (unsigned)q3, p7 = (unsigned)(q3 >> 32);
    uint4 h, l;
    h.x = (p0 & 0xFFFFu) | (p1 << 16);
    h.y = (p2 & 0xFFFFu) | (p3 << 16);
    h.z = (p4 & 0xFFFFu) | (p5 << 16);
    h.w = (p6 & 0xFFFFu) | (p7 << 16);
    l.x = (p0 >> 16) | (p1 & 0xFFFF0000u);
    l.y = (p2 >> 16) | (p3 & 0xFFFF0000u);
    l.z = (p4 >> 16) | (p5 & 0xFFFF0000u);
    l.w = (p6 >> 16) | (p7 & 0xFFFF0000u);
    Ah = __builtin_bit_cast(bf16x8, h);
    Al = __builtin_bit_cast(bf16x8, l);
}

// W packing: BY-VALUE return of two u32x4
struct WPair { u32x4 hi, lo; };
__device__ __forceinline__ WPair packW(const float* src) {
    float4 w0 = *(const float4*)src;
    float4 w1 = *(const float4*)(src + 16);
    u32x4 qh;
    qh.x = pack2(w0.x, w0.y); qh.y = pack2(w0.z, w0.w);
    qh.z = pack2(w1.x, w1.y); qh.w = pack2(w1.z, w1.w);
    float r0 = w0.x - bf2f((unsigned short)(qh.x & 0xFFFF));
    float r1 = w0.y - bf2f((unsigned short)(qh.x >> 16));
    float r2 = w0.z - bf2f((unsigned short)(qh.y & 0xFFFF));
    float r3 = w0.w - bf2f((unsigned short)(qh.y >> 16));
    float r4 = w1.x - bf2f((unsigned short)(qh.z & 0xFFFF));
    float r5 = w1.y - bf2f((unsigned short)(qh.z >> 16));
    float r6 = w1.z - bf2f((unsigned short)(qh.w & 0xFFFF));
    float r7 = w1.w - bf2f((unsigned short)(qh.w >> 16));
    u32x4 ql;
    ql.x = pack2(r0, r1); ql.y = pack2(r2, r3);
    ql.z = pack2(r4, r5); ql.w = pack2(r6, r7);
    WPair out; out.hi = qh; out.lo = ql;
    return out;
}

// ---- prep: context max-pool, lang embed, h0 pack, flag reset ----
__global__ void k_prep(const float* __restrict__ enc_outs, const float* __restrict__ embed,
                       const int* __restrict__ langs, const float* __restrict__ h0,
                       float* __restrict__ si, unsigned int* __restrict__ hp,
                       unsigned int* __restrict__ flags) {
    int tid = blockIdx.x * blockDim.x + threadIdx.x;
    int np = gridDim.x * blockDim.x;
    for (int i = tid; i < NBLK * 16; i += np)
        flags[i] = 0u;
    for (int i = tid; i < B_DIM * ENC2; i += np) {        // context = max over S
        int b = i >> 10, e = i & 1023;
        float m = -3.4e38f;
        for (int s = 0; s < S_DIM; ++s)
            m = fmaxf(m, enc_outs[(s * B_DIM + b) * ENC2 + e]);
        si[b * SI_DIM + E_DIM + e] = m;
    }
    for (int i = tid; i < B_DIM * E_DIM; i += np) {       // lang embedding
        int b = i >> 9, e = i & 511;
        si[b * SI_DIM + e] = embed[(long)langs[b] * E_DIM + e];
    }
    for (int i = tid; i < B_DIM * H_DIM; i += np) {       // h0 pack (parity 0)
        float h = h0[i];
        unsigned short hi = f2bf(h);
        unsigned short lo = f2bf(h - bf2f(hi));
        hp[i] = (unsigned)hi | ((unsigned)lo << 16);
    }
}

// ---- gather token embeddings -> x hi/lo [T*B][512], row r = t*32+b ----
__global__ void k_gather_x(const float* __restrict__ embed, const int* __restrict__ tok,
                           unsigned short* __restrict__ xhi, unsigned short* __restrict__ xlo) {
    int r = blockIdx.x;
    int t = r >> 5, b = r & 31;
    long row = tok[b * T_DIM + t];
    const float4* src = (const float4*)(embed + row * E_DIM);
    ushort4* dh = (ushort4*)(xhi + (long)r * E_DIM);
    ushort4* dl = (ushort4*)(xlo + (long)r * E_DIM);
    for (int i = threadIdx.x; i < E_DIM / 4; i += blockDim.x) {
        float4 v = src[i];
        ushort4 h, l;
        h.x = f2bf(v.x); l.x = f2bf(v.x - bf2f(h.x));
        h.y = f2bf(v.y); l.y = f2bf(v.y - bf2f(h.y));
        h.z = f2bf(v.z); l.z = f2bf(v.z - bf2f(h.z));
        h.w = f2bf(v.w); l.w = f2bf(v.w - bf2f(h.w));
        dh[i] = h; dl[i] = l;
    }
}

// per-k-iteration macros over NAMED W fragment variables (u32x4 -> bf16x8)
#define HH_IT(IT) do { \
    bf16x8 Ah0, Al0, Ah1, Al1; \
    lda_pair(hrow0 + IT * 32, Ah0, Al0); \
    lda_pair(hrow1 + IT * 32, Ah1, Al1); \
    acc00 = mfma16(Ah0, tofrag(Wh0##IT), acc00); \
    acc00 = mfma16(Ah0, tofrag(Wl0##IT), acc00); \
    acc00 = mfma16(Al0, tofrag(Wh0##IT), acc00); \
    acc01 = mfma16(Ah1, tofrag(Wh0##IT), acc01); \
    acc01 = mfma16(Ah1, tofrag(Wl0##IT), acc01); \
    acc01 = mfma16(Al1, tofrag(Wh0##IT), acc01); \
    acc10 = mfma16(Ah0, tofrag(Wh1##IT), acc10); \
    acc10 = mfma16(Ah0, tofrag(Wl1##IT), acc10); \
    acc10 = mfma16(Al0, tofrag(Wh1##IT), acc10); \
    acc11 = mfma16(Ah1, tofrag(Wh1##IT), acc11); \
    acc11 = mfma16(Ah1, tofrag(Wl1##IT), acc11); \
    acc11 = mfma16(Al1, tofrag(Wh1##IT), acc11); \
} while (0)

#define XX_IT(IT) do { \
    bf16x8 Ah0 = load_frag(ax  + IT * 32); \
    bf16x8 Ah1 = load_frag(ax  + 16 * E_DIM + IT * 32); \
    bf16x8 Al0 = load_frag(axl + IT * 32); \
    bf16x8 Al1 = load_frag(axl + 16 * E_DIM + IT * 32); \
    acc00 = mfma16(Ah0, tofrag(Xh0##IT), acc00); \
    acc00 = mfma16(Ah0, tofrag(Xl0##IT), acc00); \
    acc00 = mfma16(Al0, tofrag(Xh0##IT), acc00); \
    acc01 = mfma16(Ah1, tofrag(Xh0##IT), acc01); \
    acc01 = mfma16(Ah1, tofrag(Xl0##IT), acc01); \
    acc01 = mfma16(Al1, tofrag(Xh0##IT), acc01); \
    acc10 = mfma16(Ah0, tofrag(Xh1##IT), acc10); \
    acc10 = mfma16(Ah0, tofrag(Xl1##IT), acc10); \
    acc10 = mfma16(Al0, tofrag(Xh1##IT), acc10); \
    acc11 = mfma16(Ah1, tofrag(Xh1##IT), acc11); \
    acc11 = mfma16(Ah1, tofrag(Xl1##IT), acc11); \
    acc11 = mfma16(Al1, tofrag(Xh1##IT), acc11); \
} while (0)

#define PK_HH(F, IT) { WPair p = packW(W_hh + (long)rowf##F * H_DIM + (wv * KHW + IT * 32 + 4 * lg)); \
                       Wh##F##IT = p.hi; Wl##F##IT = p.lo; }
#define PK_X(F, IT)  { WPair p = packW(W_ih + (long)rowf##F * 2048 + (wv * KXW + IT * 32 + 4 * lg)); \
                       Xh##F##IT = p.hi; Xl##F##IT = p.lo; }

// ---- persistent LSTM: W pinned in registers, fence-free flag barrier ----
__global__ __launch_bounds__(NTHR, 2) void k_lstm(
        const unsigned short* __restrict__ xhi, const unsigned short* __restrict__ xlo,
        unsigned int* __restrict__ hp,
        const float* __restrict__ si, const float* __restrict__ W_ih,
        const float* __restrict__ W_hh, const float* __restrict__ b_ih,
        const float* __restrict__ b_hh, const float* __restrict__ c0,
        float* __restrict__ out, unsigned int* __restrict__ flags) {
    __shared__ f32x4 red[8][2][2][64];     // [wave][frag][Ahalf][lane] partials (32 KB)
    __shared__ float gbuf[4][B_DIM][JT];   // gates (4 KB)
    __shared__ float sgl[4][B_DIM][JT];    // static gate bias (4 KB)

    const int tid = threadIdx.x;
    const int wv = tid >> 6, l = tid & 63, lr = l & 15, lg = l >> 4;
    const int jb = blockIdx.x * JT;

    // ---- prologue 1: static gate bias sg (fp32, block-local) ----
    {
        int c = tid >> 4, bp = tid & 15;        // c: 0..31 gate-col, bp: batch pair base
        int gate = c >> 3, jl = c & 7;
        long grow = (long)(gate * H_DIM + jb + jl);
        const float* wrow = W_ih + grow * 2048 + E_DIM;
        const float* s0 = si + bp * SI_DIM;
        const float* s1 = si + (bp + 16) * SI_DIM;
        float a0 = 0.f, a1 = 0.f;
        for (int k = 0; k < SI_DIM; k += 4) {
            float4 w  = *(const float4*)(wrow + k);
            float4 x0 = *(const float4*)(s0 + k);
            float4 x1 = *(const float4*)(s1 + k);
            a0 += w.x * x0.x + w.y * x0.y + w.z * x0.z + w.w * x0.w;
            a1 += w.x * x1.x + w.y * x1.y + w.z * x1.z + w.w * x1.w;
        }
        float bias = b_ih[grow] + b_hh[grow];
        sgl[gate][bp][jl] = a0 + bias;
        sgl[gate][bp + 16][jl] = a1 + bias;
    }

    // ---- prologue 2: W slices into NAMED register fragments, then PIN them ----
    // frag f covers gate-cols: gate = 2f + (lr>>3), j = jb + (lr&7)
    const int rowf0 = ((lr >> 3)) * H_DIM + jb + (lr & 7);
    const int rowf1 = (2 + (lr >> 3)) * H_DIM + jb + (lr & 7);

    u32x4 Wh00, Wh01, Wh02, Wh03, Wh04, Wh05, Wh06, Wh07;
    u32x4 Wh10, Wh11, Wh12, Wh13, Wh14, Wh15, Wh16, Wh17;
    u32x4 Wl00, Wl01, Wl02, Wl03, Wl04, Wl05, Wl06, Wl07;
    u32x4 Wl10, Wl11, Wl12, Wl13, Wl14, Wl15, Wl16, Wl17;
    u32x4 Xh00, Xh01, Xh10, Xh11, Xl00, Xl01, Xl10, Xl11;

    PK_HH(0, 0) PK_HH(0, 1) PK_HH(0, 2) PK_HH(0, 3)
    PK_HH(0, 4) PK_HH(0, 5) PK_HH(0, 6) PK_HH(0, 7)
    PK_HH(1, 0) PK_HH(1, 1) PK_HH(1, 2) PK_HH(1, 3)
    PK_HH(1, 4) PK_HH(1, 5) PK_HH(1, 6) PK_HH(1, 7)
    PK_X(0, 0) PK_X(0, 1) PK_X(1, 0) PK_X(1, 1)

    OPAQUE(Wh00); OPAQUE(Wh01); OPAQUE(Wh02); OPAQUE(Wh03);
    OPAQUE(Wh04); OPAQUE(Wh05); OPAQUE(Wh06); OPAQUE(Wh07);
    OPAQUE(Wh10); OPAQUE(Wh11); OPAQUE(Wh12); OPAQUE(Wh13);
    OPAQUE(Wh14); OPAQUE(Wh15); OPAQUE(Wh16); OPAQUE(Wh17);
    OPAQUE(Wl00); OPAQUE(Wl01); OPAQUE(Wl02); OPAQUE(Wl03);
    OPAQUE(Wl04); OPAQUE(Wl05); OPAQUE(Wl06); OPAQUE(Wl07);
    OPAQUE(Wl10); OPAQUE(Wl11); OPAQUE(Wl12); OPAQUE(Wl13);
    OPAQUE(Wl14); OPAQUE(Wl15); OPAQUE(Wl16); OPAQUE(Wl17);
    OPAQUE(Xh00); OPAQUE(Xh01); OPAQUE(Xh10); OPAQUE(Xh11);
    OPAQUE(Xl00); OPAQUE(Xl01); OPAQUE(Xl10); OPAQUE(Xl11);

    // ---- prologue 3: cell state in register (thread<256 owns cell (b, jb+jl)) ----
    const int ab = tid >> 3, ajl = tid & 7;     // activation mapping
    float creg = 0.f;
    if (tid < 256) creg = c0[ab * H_DIM + jb + ajl];

    __syncthreads();   // sgl ready

    // ---- time loop ----
    #pragma unroll 1
    for (int t = 0; t < T_DIM; ++t) {
        f32x4 acc00 = {}, acc01 = {}, acc10 = {}, acc11 = {};  // [frag][Ahalf]

        // input term FIRST (independent of h_t; overlaps other blocks' tails)
        {
            const unsigned short* ax  = xhi + (size_t)(t * B_DIM + lr) * E_DIM + 4 * lg + wv * KXW;
            const unsigned short* axl = xlo + (size_t)(t * B_DIM + lr) * E_DIM + 4 * lg + wv * KXW;
            XX_IT(0); XX_IT(1);
        }

        // wait until all blocks published h_t (t>0). Wave 0 polls all 256 flags.
        if (t > 0) {
            if (tid < 64) {
                const unsigned tgt = (unsigned)t;
                for (;;) {
                    bool ok = true;
                    #pragma unroll
                    for (int i = 0; i < 4; ++i) {
                        unsigned v = __hip_atomic_load(
                            flags + (size_t)(tid + 64 * i) * 16,
                            __ATOMIC_RELAXED, __HIP_MEMORY_SCOPE_AGENT);
                        ok = ok && (v >= tgt);
                    }
                    if (__all(ok)) break;
                    __builtin_amdgcn_s_sleep(2);
                }
            }
            __syncthreads();   // h reads below use bypass loads; no cache inv needed
        }

        const unsigned int* hp_cur = hp + (size_t)(t & 1) * HB;
        unsigned int* hp_nxt = hp + (size_t)((t & 1) ^ 1) * HB;

        // recurrent term: this wave's K-slice of W_hh (h via LLC bypass loads)
        {
            const unsigned int* hrow0 = hp_cur + lr * H_DIM + 4 * lg + wv * KHW;
            const unsigned int* hrow1 = hrow0 + 16 * H_DIM;
            HH_IT(0); HH_IT(1); HH_IT(2); HH_IT(3);
            HH_IT(4); HH_IT(5); HH_IT(6); HH_IT(7);
        }

        // cross-wave K reduction
        red[wv][0][0][l] = acc00; red[wv][0][1][l] = acc01;
        red[wv][1][0][l] = acc10; red[wv][1][1][l] = acc11;
        __syncthreads();
        #pragma unroll
        for (int o = tid; o < 1024; o += NTHR) {
            int f = o >> 9, m = (o >> 8) & 1, l2 = (o >> 2) & 63, r = o & 3;
            float s = 0.f;
            #pragma unroll
            for (int w = 0; w < 8; ++w) s += red[w][f][m][l2][r];
            int b = 16 * m + 4 * (l2 >> 4) + r;
            int c = l2 & 15;
            int gate = 2 * f + (c >> 3), jl = c & 7;
            gbuf[gate][b][jl] = s + sgl[gate][b][jl];
        }
        __syncthreads();

        // activation: thread<256 owns cell (ab, jb+ajl); c stays in register.
        // h published as packed u32 write-through (agent scope, no L2 dirty).
        if (tid < 256) {
            float iv = gbuf[0][ab][ajl], fv = gbuf[1][ab][ajl];
            float gv = gbuf[2][ab][ajl], ov = gbuf[3][ab][ajl];
            float cn = sigf(fv) * creg + sigf(iv) * tanhf(gv);
            float hn = sigf(ov) * tanhf(cn);
            creg = cn;
            int j = jb + ajl;
            unsigned short hi = f2bf(hn);
            unsigned short lo = f2bf(hn - bf2f(hi));
            __hip_atomic_store(hp_nxt + ab * H_DIM + j,
                               (unsigned)hi | ((unsigned)lo << 16),
                               __ATOMIC_RELAXED, __HIP_MEMORY_SCOPE_AGENT);
            out[(size_t)t * HB + ab * H_DIM + j] = hn;
        }

        // arrive: drain our stores to the coherence point, then one flag store
        if (t < T_DIM - 1) {
            asm volatile("s_waitcnt vmcnt(0)" ::: "memory");
            __syncthreads();
            if (tid == 0)
                __hip_atomic_store(flags + (size_t)blockIdx.x * 16,
                                   (unsigned)(t + 1), __ATOMIC_RELAXED,
                                   __HIP_MEMORY_SCOPE_AGENT);
        }
    }
}

extern "C" void kernel_launch(void* const* d_in, const int* in_sizes, int n_in,
                              void* d_out, int out_size, void* d_ws, size_t ws_size,
                              hipStream_t stream) {
    const float* embed    = (const float*)d_in[0];
    const float* enc_outs = (const float*)d_in[1];
    const float* h0       = (const float*)d_in[2];
    const float* c0       = (const float*)d_in[3];
    const float* W_ih     = (const float*)d_in[4];
    const float* W_hh     = (const float*)d_in[5];
    const float* b_ih     = (const float*)d_in[6];
    const float* b_hh     = (const float*)d_in[7];
    const int*   tok      = (const int*)d_in[8];
    const int*   langs    = (const int*)d_in[9];
    float* out = (float*)d_out;

    char* ws = (char*)d_ws;
    unsigned short* x_hi = (unsigned short*)(ws + 0);
    unsigned short* x_lo = (unsigned short*)(ws + 4194304);
    unsigned int*   hp   = (unsigned int*)(ws + 8388608);
    float*          si   = (float*)(ws + 8912896);
    unsigned int* flags  = (unsigned int*)(ws + 9109504);

    hipLaunchKernelGGL(k_prep, dim3(512), dim3(256), 0, stream,
                       enc_outs, embed, langs, h0, si, hp, flags);
    hipLaunchKernelGGL(k_gather_x, dim3(T_DIM * B_DIM), dim3(128), 0, stream,
                       embed, tok, x_hi, x_lo);
    hipLaunchKernelGGL(k_lstm, dim3(NBLK), dim3(NTHR), 0, stream,
                       x_hi, x_lo, hp, si, W_ih, W_hh, b_ih, b_hh, c0,
                       out, flags);
}

// Round 8
// 1551.270 us; speedup vs baseline: 1.7383x; 1.7383x over previous
//
#include <hip/hip_runtime.h>
#include <math.h>

// ---------------- problem dims ----------------
#define E_DIM 512     // embedding dim
#define H_DIM 2048    // hidden
#define G_DIM 8192    // 4*H
#define B_DIM 32      // batch
#define T_DIM 128     // target time
#define S_DIM 128     // source time
#define ENC2  1024    // 2*encoder_hidden
#define SI_DIM 1536   // E + 2*enc (static input)

#define NBLK 256      // persistent blocks (1 per CU)
#define NTHR 512      // 8 waves
#define JT   8        // hidden cols per block
#define KHW  (H_DIM/8)   // 256: W_hh K-slice per wave
#define KXW  (E_DIM/8)   // 64:  W_ih K-slice per wave
#define XT_T 16384       // u32 per timestep in xt:  128 groups * 32 b * 4
#define HTB  65536       // u32 per ht buffer:       512 groups * 32 b * 4

// ---------------- workspace layout (bytes) ----------------
// xt    u32 [128][128][32][4] @ 0        (8388608)  packed x: hi|lo, k-group-major
// ht    u32 2x[512][32][4]    @ 8388608  (524288)   packed h, k-group-major
// si    f32  [32][1536]       @ 8912896  (196608)
// flags u32  [256]x16         @ 9109504  (16384)    64B-strided arrival flags
// total ~9.1 MB

typedef __bf16 bf16_t;
typedef bf16_t bf16x8 __attribute__((ext_vector_type(8)));
typedef float f32x4 __attribute__((ext_vector_type(4)));
typedef unsigned int u32x4 __attribute__((ext_vector_type(4)));

__device__ __forceinline__ unsigned short f2bf(float x) {
    unsigned u = __float_as_uint(x);
    u += 0x7FFFu + ((u >> 16) & 1u);   // RNE
    return (unsigned short)(u >> 16);
}
__device__ __forceinline__ float bf2f(unsigned short s) {
    return __uint_as_float(((unsigned)s) << 16);
}
__device__ __forceinline__ unsigned pack2(float a, float b) {
    return (unsigned)f2bf(a) | ((unsigned)f2bf(b) << 16);
}
// pack one float into (hi | lo<<16)
__device__ __forceinline__ unsigned packu(float x) {
    unsigned short hi = f2bf(x);
    unsigned short lo = f2bf(x - bf2f(hi));
    return (unsigned)hi | ((unsigned)lo << 16);
}
__device__ __forceinline__ f32x4 mfma16(bf16x8 a, bf16x8 b, f32x4 c) {
    return __builtin_amdgcn_mfma_f32_16x16x32_bf16(a, b, c, 0, 0, 0);
}
__device__ __forceinline__ bf16x8 tofrag(u32x4 q) {
    return __builtin_bit_cast(bf16x8, q);
}
__device__ __forceinline__ float sigf(float x) { return 1.f / (1.f + expf(-x)); }

#define OPAQUE(v) asm volatile("" : "+v"(v))

// build hi/lo A-fragments from two coalesced dwordx4 of packed (hi|lo) u32
__device__ __forceinline__ void unpack_pair(uint4 qA, uint4 qB, bf16x8& Ah, bf16x8& Al) {
    uint4 h, l;
    h.x = (qA.x & 0xFFFFu) | (qA.y << 16);
    h.y = (qA.z & 0xFFFFu) | (qA.w << 16);
    h.z = (qB.x & 0xFFFFu) | (qB.y << 16);
    h.w = (qB.z & 0xFFFFu) | (qB.w << 16);
    l.x = (qA.x >> 16) | (qA.y & 0xFFFF0000u);
    l.y = (qA.z >> 16) | (qA.w & 0xFFFF0000u);
    l.z = (qB.x >> 16) | (qB.y & 0xFFFF0000u);
    l.w = (qB.z >> 16) | (qB.w & 0xFFFF0000u);
    Ah = __builtin_bit_cast(bf16x8, h);
    Al = __builtin_bit_cast(bf16x8, l);
}

// W packing: BY-VALUE return of two u32x4
struct WPair { u32x4 hi, lo; };
__device__ __forceinline__ WPair packW(const float* src) {
    float4 w0 = *(const float4*)src;
    float4 w1 = *(const float4*)(src + 16);
    u32x4 qh;
    qh.x = pack2(w0.x, w0.y); qh.y = pack2(w0.z, w0.w);
    qh.z = pack2(w1.x, w1.y); qh.w = pack2(w1.z, w1.w);
    float r0 = w0.x - bf2f((unsigned short)(qh.x & 0xFFFF));
    float r1 = w0.y - bf2f((unsigned short)(qh.x >> 16));
    float r2 = w0.z - bf2f((unsigned short)(qh.y & 0xFFFF));
    float r3 = w0.w - bf2f((unsigned short)(qh.y >> 16));
    float r4 = w1.x - bf2f((unsigned short)(qh.z & 0xFFFF));
    float r5 = w1.y - bf2f((unsigned short)(qh.z >> 16));
    float r6 = w1.z - bf2f((unsigned short)(qh.w & 0xFFFF));
    float r7 = w1.w - bf2f((unsigned short)(qh.w >> 16));
    u32x4 ql;
    ql.x = pack2(r0, r1); ql.y = pack2(r2, r3);
    ql.z = pack2(r4, r5); ql.w = pack2(r6, r7);
    WPair out; out.hi = qh; out.lo = ql;
    return out;
}

// ---- prep: context max-pool, lang embed, h0 pack (transposed), flag reset ----
__global__ void k_prep(const float* __restrict__ enc_outs, const float* __restrict__ embed,
                       const int* __restrict__ langs, const float* __restrict__ h0,
                       float* __restrict__ si, unsigned int* __restrict__ ht,
                       unsigned int* __restrict__ flags) {
    int tid = blockIdx.x * blockDim.x + threadIdx.x;
    int np = gridDim.x * blockDim.x;
    for (int i = tid; i < NBLK * 16; i += np)
        flags[i] = 0u;
    for (int i = tid; i < B_DIM * ENC2; i += np) {        // context = max over S
        int b = i >> 10, e = i & 1023;
        float m = -3.4e38f;
        for (int s = 0; s < S_DIM; ++s)
            m = fmaxf(m, enc_outs[(s * B_DIM + b) * ENC2 + e]);
        si[b * SI_DIM + E_DIM + e] = m;
    }
    for (int i = tid; i < B_DIM * E_DIM; i += np) {       // lang embedding
        int b = i >> 9, e = i & 511;
        si[b * SI_DIM + e] = embed[(long)langs[b] * E_DIM + e];
    }
    for (int i = tid; i < B_DIM * H_DIM; i += np) {       // h0 pack, transposed layout
        int b = i >> 11, k = i & 2047;
        ht[(k >> 2) * 128 + b * 4 + (k & 3)] = packu(h0[i]);
    }
}

// ---- gather token embeddings -> xt[t][g][b][4] packed u32; block r = t*32+b ----
__global__ void k_gather_x(const float* __restrict__ embed, const int* __restrict__ tok,
                           unsigned int* __restrict__ xt) {
    int r = blockIdx.x;
    int t = r >> 5, b = r & 31;
    long row = tok[b * T_DIM + t];
    const float4* src = (const float4*)(embed + row * E_DIM);
    unsigned int* dst = xt + (size_t)t * XT_T;
    for (int g = threadIdx.x; g < 128; g += blockDim.x) {
        float4 v = src[g];
        uint4 q;
        q.x = packu(v.x); q.y = packu(v.y); q.z = packu(v.z); q.w = packu(v.w);
        *(uint4*)(dst + g * 128 + b * 4) = q;
    }
}

// unified A-term macro: coalesced dwordx4 cached loads from k-group-major layout
// BPTR: u32 base for this wave's k-slice; frag names WH/WL ## f ## IT
#define A_IT(BPTR, WH, WL, IT) do { \
    const unsigned int* bp_ = (BPTR) + (IT) * 1024; \
    uint4 qA0 = *(const uint4*)(bp_ + lg * 128 + lr4); \
    uint4 qB0 = *(const uint4*)(bp_ + 512 + lg * 128 + lr4); \
    uint4 qA1 = *(const uint4*)(bp_ + lg * 128 + lr4 + 64); \
    uint4 qB1 = *(const uint4*)(bp_ + 512 + lg * 128 + lr4 + 64); \
    bf16x8 Ah0, Al0, Ah1, Al1; \
    unpack_pair(qA0, qB0, Ah0, Al0); \
    unpack_pair(qA1, qB1, Ah1, Al1); \
    acc00 = mfma16(Ah0, tofrag(WH##0##IT), acc00); \
    acc00 = mfma16(Ah0, tofrag(WL##0##IT), acc00); \
    acc00 = mfma16(Al0, tofrag(WH##0##IT), acc00); \
    acc01 = mfma16(Ah1, tofrag(WH##0##IT), acc01); \
    acc01 = mfma16(Ah1, tofrag(WL##0##IT), acc01); \
    acc01 = mfma16(Al1, tofrag(WH##0##IT), acc01); \
    acc10 = mfma16(Ah0, tofrag(WH##1##IT), acc10); \
    acc10 = mfma16(Ah0, tofrag(WL##1##IT), acc10); \
    acc10 = mfma16(Al0, tofrag(WH##1##IT), acc10); \
    acc11 = mfma16(Ah1, tofrag(WH##1##IT), acc11); \
    acc11 = mfma16(Ah1, tofrag(WL##1##IT), acc11); \
    acc11 = mfma16(Al1, tofrag(WH##1##IT), acc11); \
} while (0)

#define PK_HH(F, IT) { WPair p = packW(W_hh + (long)rowf##F * H_DIM + (wv * KHW + IT * 32 + 4 * lg)); \
                       Wh##F##IT = p.hi; Wl##F##IT = p.lo; }
#define PK_X(F, IT)  { WPair p = packW(W_ih + (long)rowf##F * 2048 + (wv * KXW + IT * 32 + 4 * lg)); \
                       Xh##F##IT = p.hi; Xl##F##IT = p.lo; }

// ---- persistent LSTM: W in registers, coalesced L2-cached h + per-step acquire ----
__global__ __launch_bounds__(NTHR, 2) void k_lstm(
        const unsigned int* __restrict__ xt, unsigned int* __restrict__ ht,
        const float* __restrict__ si, const float* __restrict__ W_ih,
        const float* __restrict__ W_hh, const float* __restrict__ b_ih,
        const float* __restrict__ b_hh, const float* __restrict__ c0,
        float* __restrict__ out, unsigned int* __restrict__ flags) {
    __shared__ f32x4 red[8][2][2][64];     // [wave][frag][Ahalf][lane] partials (32 KB)
    __shared__ float gbuf[4][B_DIM][JT];   // gates (4 KB)
    __shared__ float sgl[4][B_DIM][JT];    // static gate bias (4 KB)

    const int tid = threadIdx.x;
    const int wv = tid >> 6, l = tid & 63, lr = l & 15, lg = l >> 4;
    const int lr4 = lr * 4;
    const int jb = blockIdx.x * JT;

    // ---- prologue 1: static gate bias sg (fp32, block-local) ----
    {
        int c = tid >> 4, bp = tid & 15;
        int gate = c >> 3, jl = c & 7;
        long grow = (long)(gate * H_DIM + jb + jl);
        const float* wrow = W_ih + grow * 2048 + E_DIM;
        const float* s0 = si + bp * SI_DIM;
        const float* s1 = si + (bp + 16) * SI_DIM;
        float a0 = 0.f, a1 = 0.f;
        for (int k = 0; k < SI_DIM; k += 4) {
            float4 w  = *(const float4*)(wrow + k);
            float4 x0 = *(const float4*)(s0 + k);
            float4 x1 = *(const float4*)(s1 + k);
            a0 += w.x * x0.x + w.y * x0.y + w.z * x0.z + w.w * x0.w;
            a1 += w.x * x1.x + w.y * x1.y + w.z * x1.z + w.w * x1.w;
        }
        float bias = b_ih[grow] + b_hh[grow];
        sgl[gate][bp][jl] = a0 + bias;
        sgl[gate][bp + 16][jl] = a1 + bias;
    }

    // ---- prologue 2: W slices into NAMED register fragments, pinned ----
    const int rowf0 = ((lr >> 3)) * H_DIM + jb + (lr & 7);
    const int rowf1 = (2 + (lr >> 3)) * H_DIM + jb + (lr & 7);

    u32x4 Wh00, Wh01, Wh02, Wh03, Wh04, Wh05, Wh06, Wh07;
    u32x4 Wh10, Wh11, Wh12, Wh13, Wh14, Wh15, Wh16, Wh17;
    u32x4 Wl00, Wl01, Wl02, Wl03, Wl04, Wl05, Wl06, Wl07;
    u32x4 Wl10, Wl11, Wl12, Wl13, Wl14, Wl15, Wl16, Wl17;
    u32x4 Xh00, Xh01, Xh10, Xh11, Xl00, Xl01, Xl10, Xl11;

    PK_HH(0, 0) PK_HH(0, 1) PK_HH(0, 2) PK_HH(0, 3)
    PK_HH(0, 4) PK_HH(0, 5) PK_HH(0, 6) PK_HH(0, 7)
    PK_HH(1, 0) PK_HH(1, 1) PK_HH(1, 2) PK_HH(1, 3)
    PK_HH(1, 4) PK_HH(1, 5) PK_HH(1, 6) PK_HH(1, 7)
    PK_X(0, 0) PK_X(0, 1) PK_X(1, 0) PK_X(1, 1)

    OPAQUE(Wh00); OPAQUE(Wh01); OPAQUE(Wh02); OPAQUE(Wh03);
    OPAQUE(Wh04); OPAQUE(Wh05); OPAQUE(Wh06); OPAQUE(Wh07);
    OPAQUE(Wh10); OPAQUE(Wh11); OPAQUE(Wh12); OPAQUE(Wh13);
    OPAQUE(Wh14); OPAQUE(Wh15); OPAQUE(Wh16); OPAQUE(Wh17);
    OPAQUE(Wl00); OPAQUE(Wl01); OPAQUE(Wl02); OPAQUE(Wl03);
    OPAQUE(Wl04); OPAQUE(Wl05); OPAQUE(Wl06); OPAQUE(Wl07);
    OPAQUE(Wl10); OPAQUE(Wl11); OPAQUE(Wl12); OPAQUE(Wl13);
    OPAQUE(Wl14); OPAQUE(Wl15); OPAQUE(Wl16); OPAQUE(Wl17);
    OPAQUE(Xh00); OPAQUE(Xh01); OPAQUE(Xh10); OPAQUE(Xh11);
    OPAQUE(Xl00); OPAQUE(Xl01); OPAQUE(Xl10); OPAQUE(Xl11);

    // ---- prologue 3: cell state in register ----
    const int ab = tid >> 3, ajl = tid & 7;
    float creg = 0.f;
    if (tid < 256) creg = c0[ab * H_DIM + jb + ajl];

    __syncthreads();   // sgl ready

    // ---- time loop ----
    #pragma unroll 1
    for (int t = 0; t < T_DIM; ++t) {
        f32x4 acc00 = {}, acc01 = {}, acc10 = {}, acc11 = {};  // [frag][Ahalf]

        // input term FIRST (constant data; overlaps other blocks' tails)
        {
            const unsigned int* xb = xt + (size_t)t * XT_T + wv * 2048;
            A_IT(xb, Xh, Xl, 0); A_IT(xb, Xh, Xl, 1);
        }

        // wait until all blocks published h_t (t>0); then acquire -> L1/L2 inv
        if (t > 0) {
            if (tid < 64) {
                const unsigned tgt = (unsigned)t;
                for (;;) {
                    bool ok = true;
                    #pragma unroll
                    for (int i = 0; i < 4; ++i) {
                        unsigned v = __hip_atomic_load(
                            flags + (size_t)(tid + 64 * i) * 16,
                            __ATOMIC_RELAXED, __HIP_MEMORY_SCOPE_AGENT);
                        ok = ok && (v >= tgt);
                    }
                    if (__all(ok)) break;
                    __builtin_amdgcn_s_sleep(2);
                }
                // acquire: invalidate stale L1/L2 so cached h reads see LLC
                unsigned d = __hip_atomic_load(flags, __ATOMIC_ACQUIRE,
                                               __HIP_MEMORY_SCOPE_AGENT);
                asm volatile("" :: "v"(d));
            }
            __syncthreads();
        }

        const unsigned int* ht_cur = ht + (size_t)(t & 1) * HTB;
        unsigned int* ht_nxt = ht + (size_t)((t & 1) ^ 1) * HTB;

        // recurrent term: coalesced cached dwordx4 loads (L2-shared per XCD)
        {
            const unsigned int* hb_ = ht_cur + wv * 8192;
            A_IT(hb_, Wh, Wl, 0); A_IT(hb_, Wh, Wl, 1);
            A_IT(hb_, Wh, Wl, 2); A_IT(hb_, Wh, Wl, 3);
            A_IT(hb_, Wh, Wl, 4); A_IT(hb_, Wh, Wl, 5);
            A_IT(hb_, Wh, Wl, 6); A_IT(hb_, Wh, Wl, 7);
        }

        // cross-wave K reduction
        red[wv][0][0][l] = acc00; red[wv][0][1][l] = acc01;
        red[wv][1][0][l] = acc10; red[wv][1][1][l] = acc11;
        __syncthreads();
        #pragma unroll
        for (int o = tid; o < 1024; o += NTHR) {
            int f = o >> 9, m = (o >> 8) & 1, l2 = (o >> 2) & 63, r = o & 3;
            float s = 0.f;
            #pragma unroll
            for (int w = 0; w < 8; ++w) s += red[w][f][m][l2][r];
            int b = 16 * m + 4 * (l2 >> 4) + r;
            int c = l2 & 15;
            int gate = 2 * f + (c >> 3), jl = c & 7;
            gbuf[gate][b][jl] = s + sgl[gate][b][jl];
        }
        __syncthreads();

        // activation: h published transposed as write-through packed u32
        if (tid < 256) {
            float iv = gbuf[0][ab][ajl], fv = gbuf[1][ab][ajl];
            float gv = gbuf[2][ab][ajl], ov = gbuf[3][ab][ajl];
            float cn = sigf(fv) * creg + sigf(iv) * tanhf(gv);
            float hn = sigf(ov) * tanhf(cn);
            creg = cn;
            int j = jb + ajl;
            __hip_atomic_store(ht_nxt + (j >> 2) * 128 + ab * 4 + (j & 3),
                               packu(hn), __ATOMIC_RELAXED,
                               __HIP_MEMORY_SCOPE_AGENT);
            out[(size_t)t * (B_DIM * H_DIM) + ab * H_DIM + j] = hn;
        }

        // arrive: drain stores to coherence point, then one flag store
        if (t < T_DIM - 1) {
            asm volatile("s_waitcnt vmcnt(0)" ::: "memory");
            __syncthreads();
            if (tid == 0)
                __hip_atomic_store(flags + (size_t)blockIdx.x * 16,
                                   (unsigned)(t + 1), __ATOMIC_RELAXED,
                                   __HIP_MEMORY_SCOPE_AGENT);
        }
    }
}

extern "C" void kernel_launch(void* const* d_in, const int* in_sizes, int n_in,
                              void* d_out, int out_size, void* d_ws, size_t ws_size,
                              hipStream_t stream) {
    const float* embed    = (const float*)d_in[0];
    const float* enc_outs = (const float*)d_in[1];
    const float* h0       = (const float*)d_in[2];
    const float* c0       = (const float*)d_in[3];
    const float* W_ih     = (const float*)d_in[4];
    const float* W_hh     = (const float*)d_in[5];
    const float* b_ih     = (const float*)d_in[6];
    const float* b_hh     = (const float*)d_in[7];
    const int*   tok      = (const int*)d_in[8];
    const int*   langs    = (const int*)d_in[9];
    float* out = (float*)d_out;

    char* ws = (char*)d_ws;
    unsigned int* xt    = (unsigned int*)(ws + 0);
    unsigned int* ht    = (unsigned int*)(ws + 8388608);
    float*        si    = (float*)(ws + 8912896);
    unsigned int* flags = (unsigned int*)(ws + 9109504);

    hipLaunchKernelGGL(k_prep, dim3(512), dim3(256), 0, stream,
                       enc_outs, embed, langs, h0, si, ht, flags);
    hipLaunchKernelGGL(k_gather_x, dim3(T_DIM * B_DIM), dim3(128), 0, stream,
                       embed, tok, xt);
    hipLaunchKernelGGL(k_lstm, dim3(NBLK), dim3(NTHR), 0, stream,
                       xt, ht, si, W_ih, W_hh, b_ih, b_hh, c0,
                       out, flags);
}

// Round 9
// 1320.410 us; speedup vs baseline: 2.0423x; 1.1748x over previous
//
#include <hip/hip_runtime.h>
#include <math.h>

// ---------------- problem dims ----------------
#define E_DIM 512     // embedding dim
#define H_DIM 2048    // hidden
#define G_DIM 8192    // 4*H
#define B_DIM 32      // batch
#define T_DIM 128     // target time
#define S_DIM 128     // source time
#define ENC2  1024    // 2*encoder_hidden
#define SI_DIM 1536   // E + 2*enc (static input)

#define NBLK 256      // persistent blocks (1 per CU)
#define NTHR 512      // 8 waves
#define JT   8        // hidden cols per block
#define KHW  (H_DIM/8)   // 256: W_hh K-slice per wave (8 tiles of 32)
#define KXW  (E_DIM/8)   // 64:  W_ih K-slice per wave (2 tiles of 32)
#define HB   (B_DIM*H_DIM)

// fragment-order plane layout: [tile(32k)][lg(4)][b(32)][8 ushorts]
// x plane per t: 16 tiles * 4 * 32 * 8 = 16384 ushorts (32 KB)
// h plane:       64 tiles * 4 * 32 * 8 = 65536 ushorts (128 KB)

// ---------------- workspace layout (bytes) ----------------
// xh  ushort [128][16384] @ 0        (4194304)
// xl  ushort [128][16384] @ 4194304  (4194304)
// hth ushort 2x[65536]    @ 8388608  (262144)
// htl ushort 2x[65536]    @ 8650752  (262144)
// si  f32 [32][1536]      @ 8912896  (196608)
// flags u32 [256]x16      @ 9109504  (16384)
// total ~9.1 MB

typedef __bf16 bf16_t;
typedef bf16_t bf16x8 __attribute__((ext_vector_type(8)));
typedef float f32x4 __attribute__((ext_vector_type(4)));
typedef unsigned int u32x4 __attribute__((ext_vector_type(4)));

__device__ __forceinline__ unsigned short f2bf(float x) {
    unsigned u = __float_as_uint(x);
    u += 0x7FFFu + ((u >> 16) & 1u);   // RNE
    return (unsigned short)(u >> 16);
}
__device__ __forceinline__ float bf2f(unsigned short s) {
    return __uint_as_float(((unsigned)s) << 16);
}
__device__ __forceinline__ unsigned pack2(float a, float b) {
    return (unsigned)f2bf(a) | ((unsigned)f2bf(b) << 16);
}
__device__ __forceinline__ f32x4 mfma16(bf16x8 a, bf16x8 b, f32x4 c) {
    return __builtin_amdgcn_mfma_f32_16x16x32_bf16(a, b, c, 0, 0, 0);
}
__device__ __forceinline__ bf16x8 tofrag(u32x4 q) {
    return __builtin_bit_cast(bf16x8, q);
}
__device__ __forceinline__ bf16x8 cat64(unsigned long long a, unsigned long long b) {
    uint4 q;
    q.x = (unsigned)a; q.y = (unsigned)(a >> 32);
    q.z = (unsigned)b; q.w = (unsigned)(b >> 32);
    return __builtin_bit_cast(bf16x8, q);
}
__device__ __forceinline__ float sigf(float x) { return 1.f / (1.f + expf(-x)); }

#define OPAQUE(v) asm volatile("" : "+v"(v))
#define ALD(p) __hip_atomic_load((p), __ATOMIC_RELAXED, __HIP_MEMORY_SCOPE_AGENT)

// W packing: BY-VALUE return of two u32x4
struct WPair { u32x4 hi, lo; };
__device__ __forceinline__ WPair packW(const float* src) {
    float4 w0 = *(const float4*)src;
    float4 w1 = *(const float4*)(src + 16);
    u32x4 qh;
    qh.x = pack2(w0.x, w0.y); qh.y = pack2(w0.z, w0.w);
    qh.z = pack2(w1.x, w1.y); qh.w = pack2(w1.z, w1.w);
    float r0 = w0.x - bf2f((unsigned short)(qh.x & 0xFFFF));
    float r1 = w0.y - bf2f((unsigned short)(qh.x >> 16));
    float r2 = w0.z - bf2f((unsigned short)(qh.y & 0xFFFF));
    float r3 = w0.w - bf2f((unsigned short)(qh.y >> 16));
    float r4 = w1.x - bf2f((unsigned short)(qh.z & 0xFFFF));
    float r5 = w1.y - bf2f((unsigned short)(qh.z >> 16));
    float r6 = w1.z - bf2f((unsigned short)(qh.w & 0xFFFF));
    float r7 = w1.w - bf2f((unsigned short)(qh.w >> 16));
    u32x4 ql;
    ql.x = pack2(r0, r1); ql.y = pack2(r2, r3);
    ql.z = pack2(r4, r5); ql.w = pack2(r6, r7);
    WPair out; out.hi = qh; out.lo = ql;
    return out;
}

// ---- prep: context max-pool, lang embed, h0 -> fragment-order planes, flags ----
__global__ void k_prep(const float* __restrict__ enc_outs, const float* __restrict__ embed,
                       const int* __restrict__ langs, const float* __restrict__ h0,
                       float* __restrict__ si, unsigned short* __restrict__ hth,
                       unsigned short* __restrict__ htl, unsigned int* __restrict__ flags) {
    int tid = blockIdx.x * blockDim.x + threadIdx.x;
    int np = gridDim.x * blockDim.x;
    for (int i = tid; i < NBLK * 16; i += np)
        flags[i] = 0u;
    for (int i = tid; i < B_DIM * ENC2; i += np) {        // context = max over S
        int b = i >> 10, e = i & 1023;
        float m = -3.4e38f;
        for (int s = 0; s < S_DIM; ++s)
            m = fmaxf(m, enc_outs[(s * B_DIM + b) * ENC2 + e]);
        si[b * SI_DIM + E_DIM + e] = m;
    }
    for (int i = tid; i < B_DIM * E_DIM; i += np) {       // lang embedding
        int b = i >> 9, e = i & 511;
        si[b * SI_DIM + e] = embed[(long)langs[b] * E_DIM + e];
    }
    for (int i = tid; i < B_DIM * H_DIM; i += np) {       // h0 into parity-0 planes
        int b = i >> 11, j = i & 2047;
        float h = h0[i];
        unsigned short hi = f2bf(h);
        unsigned short lo = f2bf(h - bf2f(hi));
        int T = j >> 5, lgp = (j & 15) >> 2, o = (j & 3) + 4 * ((j & 31) >> 4);
        int idx = ((T * 4 + lgp) * 32 + b) * 8 + o;
        hth[idx] = hi;
        htl[idx] = lo;
    }
}

// ---- gather token embeddings -> fragment-order x planes; block r = t*32+b ----
__global__ void k_gather_x(const float* __restrict__ embed, const int* __restrict__ tok,
                           unsigned short* __restrict__ xh, unsigned short* __restrict__ xl) {
    int r = blockIdx.x;
    int t = r >> 5, b = r & 31;
    long row = tok[b * T_DIM + t];
    const float4* src = (const float4*)(embed + row * E_DIM);
    unsigned* xhp = (unsigned*)(xh + (size_t)t * 16384);
    unsigned* xlp = (unsigned*)(xl + (size_t)t * 16384);
    for (int g = threadIdx.x; g < 128; g += blockDim.x) {
        float4 v = src[g];
        unsigned h01 = pack2(v.x, v.y), h23 = pack2(v.z, v.w);
        float rx = v.x - bf2f((unsigned short)(h01 & 0xFFFF));
        float ry = v.y - bf2f((unsigned short)(h01 >> 16));
        float rz = v.z - bf2f((unsigned short)(h23 & 0xFFFF));
        float rw = v.w - bf2f((unsigned short)(h23 >> 16));
        int T = g >> 3, lgp = g & 3, o0 = 4 * ((g & 7) >> 2);
        int u32i = ((T * 4 + lgp) * 32 + b) * 4 + (o0 >> 1);
        uint2 qh; qh.x = h01; qh.y = h23;
        uint2 ql; ql.x = pack2(rx, ry); ql.y = pack2(rz, rw);
        *(uint2*)(xhp + u32i) = qh;
        *(uint2*)(xlp + u32i) = ql;
    }
}

// 12 MFMAs of one 32-k tile against fragment set PFX{h,l}{0,1}IT
#define MFMA12(PH, PL, IT) \
    acc00 = mfma16(Ah0, tofrag(PH##0##IT), acc00); \
    acc00 = mfma16(Ah0, tofrag(PL##0##IT), acc00); \
    acc00 = mfma16(Al0, tofrag(PH##0##IT), acc00); \
    acc01 = mfma16(Ah1, tofrag(PH##0##IT), acc01); \
    acc01 = mfma16(Ah1, tofrag(PL##0##IT), acc01); \
    acc01 = mfma16(Al1, tofrag(PH##0##IT), acc01); \
    acc10 = mfma16(Ah0, tofrag(PH##1##IT), acc10); \
    acc10 = mfma16(Ah0, tofrag(PL##1##IT), acc10); \
    acc10 = mfma16(Al0, tofrag(PH##1##IT), acc10); \
    acc11 = mfma16(Ah1, tofrag(PH##1##IT), acc11); \
    acc11 = mfma16(Ah1, tofrag(PL##1##IT), acc11); \
    acc11 = mfma16(Al1, tofrag(PH##1##IT), acc11);

// x tile: cached uint4 loads, fragment-contiguous, zero unpack
#define AX_IT(IT) do { \
    const int fb = ((wv * 2 + (IT)) * 4 + lg) * 32 + lr; \
    bf16x8 Ah0 = __builtin_bit_cast(bf16x8, xh4[fb]); \
    bf16x8 Ah1 = __builtin_bit_cast(bf16x8, xh4[fb + 16]); \
    bf16x8 Al0 = __builtin_bit_cast(bf16x8, xl4[fb]); \
    bf16x8 Al1 = __builtin_bit_cast(bf16x8, xl4[fb + 16]); \
    MFMA12(Xh, Xl, IT) \
} while (0)

// h tile: LLC-bypass atomic u64 loads (no L2 inv needed), zero unpack
#define AH_IT(IT) do { \
    const int fb2 = (((wv * 8 + (IT)) * 4 + lg) * 32 + lr) * 2; \
    unsigned long long a0 = ALD(hh8 + fb2), a1 = ALD(hh8 + fb2 + 1); \
    unsigned long long b0 = ALD(hh8 + fb2 + 32), b1 = ALD(hh8 + fb2 + 33); \
    unsigned long long e0 = ALD(hl8 + fb2), e1 = ALD(hl8 + fb2 + 1); \
    unsigned long long d0 = ALD(hl8 + fb2 + 32), d1 = ALD(hl8 + fb2 + 33); \
    bf16x8 Ah0 = cat64(a0, a1), Ah1 = cat64(b0, b1); \
    bf16x8 Al0 = cat64(e0, e1), Al1 = cat64(d0, d1); \
    MFMA12(Wh, Wl, IT) \
} while (0)

#define PK_HH(F, IT) { WPair p = packW(W_hh + (long)rowf##F * H_DIM + (wv * KHW + IT * 32 + 4 * lg)); \
                       Wh##F##IT = p.hi; Wl##F##IT = p.lo; }
#define PK_X(F, IT)  { WPair p = packW(W_ih + (long)rowf##F * 2048 + (wv * KXW + IT * 32 + 4 * lg)); \
                       Xh##F##IT = p.hi; Xl##F##IT = p.lo; }

// ---- persistent LSTM: W in registers, per-wave partial wait, plane h path ----
__global__ __launch_bounds__(NTHR, 2) void k_lstm(
        const unsigned short* __restrict__ xh, const unsigned short* __restrict__ xl,
        unsigned short* __restrict__ hth, unsigned short* __restrict__ htl,
        const float* __restrict__ si, const float* __restrict__ W_ih,
        const float* __restrict__ W_hh, const float* __restrict__ b_ih,
        const float* __restrict__ b_hh, const float* __restrict__ c0,
        float* __restrict__ out, unsigned int* __restrict__ flags) {
    __shared__ f32x4 red[8][2][2][64];     // [wave][frag][Ahalf][lane] partials (32 KB)
    __shared__ float gbuf[4][B_DIM][JT];   // gates (4 KB)
    __shared__ float sgl[4][B_DIM][JT];    // static gate bias (4 KB)

    const int tid = threadIdx.x;
    const int wv = tid >> 6, l = tid & 63, lr = l & 15, lg = l >> 4;
    const int jb = blockIdx.x * JT;

    // ---- prologue 1: static gate bias sg (fp32, block-local) ----
    {
        int c = tid >> 4, bp = tid & 15;
        int gate = c >> 3, jl = c & 7;
        long grow = (long)(gate * H_DIM + jb + jl);
        const float* wrow = W_ih + grow * 2048 + E_DIM;
        const float* s0 = si + bp * SI_DIM;
        const float* s1 = si + (bp + 16) * SI_DIM;
        float a0 = 0.f, a1 = 0.f;
        for (int k = 0; k < SI_DIM; k += 4) {
            float4 w  = *(const float4*)(wrow + k);
            float4 x0 = *(const float4*)(s0 + k);
            float4 x1 = *(const float4*)(s1 + k);
            a0 += w.x * x0.x + w.y * x0.y + w.z * x0.z + w.w * x0.w;
            a1 += w.x * x1.x + w.y * x1.y + w.z * x1.z + w.w * x1.w;
        }
        float bias = b_ih[grow] + b_hh[grow];
        sgl[gate][bp][jl] = a0 + bias;
        sgl[gate][bp + 16][jl] = a1 + bias;
    }

    // ---- prologue 2: W slices into NAMED register fragments, pinned ----
    const int rowf0 = ((lr >> 3)) * H_DIM + jb + (lr & 7);
    const int rowf1 = (2 + (lr >> 3)) * H_DIM + jb + (lr & 7);

    u32x4 Wh00, Wh01, Wh02, Wh03, Wh04, Wh05, Wh06, Wh07;
    u32x4 Wh10, Wh11, Wh12, Wh13, Wh14, Wh15, Wh16, Wh17;
    u32x4 Wl00, Wl01, Wl02, Wl03, Wl04, Wl05, Wl06, Wl07;
    u32x4 Wl10, Wl11, Wl12, Wl13, Wl14, Wl15, Wl16, Wl17;
    u32x4 Xh00, Xh01, Xh10, Xh11, Xl00, Xl01, Xl10, Xl11;

    PK_HH(0, 0) PK_HH(0, 1) PK_HH(0, 2) PK_HH(0, 3)
    PK_HH(0, 4) PK_HH(0, 5) PK_HH(0, 6) PK_HH(0, 7)
    PK_HH(1, 0) PK_HH(1, 1) PK_HH(1, 2) PK_HH(1, 3)
    PK_HH(1, 4) PK_HH(1, 5) PK_HH(1, 6) PK_HH(1, 7)
    PK_X(0, 0) PK_X(0, 1) PK_X(1, 0) PK_X(1, 1)

    OPAQUE(Wh00); OPAQUE(Wh01); OPAQUE(Wh02); OPAQUE(Wh03);
    OPAQUE(Wh04); OPAQUE(Wh05); OPAQUE(Wh06); OPAQUE(Wh07);
    OPAQUE(Wh10); OPAQUE(Wh11); OPAQUE(Wh12); OPAQUE(Wh13);
    OPAQUE(Wh14); OPAQUE(Wh15); OPAQUE(Wh16); OPAQUE(Wh17);
    OPAQUE(Wl00); OPAQUE(Wl01); OPAQUE(Wl02); OPAQUE(Wl03);
    OPAQUE(Wl04); OPAQUE(Wl05); OPAQUE(Wl06); OPAQUE(Wl07);
    OPAQUE(Wl10); OPAQUE(Wl11); OPAQUE(Wl12); OPAQUE(Wl13);
    OPAQUE(Wl14); OPAQUE(Wl15); OPAQUE(Wl16); OPAQUE(Wl17);
    OPAQUE(Xh00); OPAQUE(Xh01); OPAQUE(Xh10); OPAQUE(Xh11);
    OPAQUE(Xl00); OPAQUE(Xl01); OPAQUE(Xl10); OPAQUE(Xl11);

    // ---- prologue 3: cell state; 128 act threads own j-pairs ----
    const int ab = (tid & 127) >> 2, ajp = (tid & 3) * 2;   // b, j-pair base
    float creg0 = 0.f, creg1 = 0.f;
    if (tid < 128) {
        creg0 = c0[ab * H_DIM + jb + ajp];
        creg1 = c0[ab * H_DIM + jb + ajp + 1];
    }

    __syncthreads();   // sgl ready

    // ---- time loop ----
    #pragma unroll 1
    for (int t = 0; t < T_DIM; ++t) {
        f32x4 acc00 = {}, acc01 = {}, acc10 = {}, acc11 = {};  // [frag][Ahalf]

        // input term FIRST (cached, hot in L2 — no invalidates exist anymore)
        {
            const uint4* xh4 = (const uint4*)(xh + (size_t)t * 16384);
            const uint4* xl4 = (const uint4*)(xl + (size_t)t * 16384);
            AX_IT(0); AX_IT(1);
        }

        // per-wave partial wait: wave wv needs h-units from blocks wv*32..wv*32+31
        if (t > 0) {
            const unsigned tgt = (unsigned)t;
            const bool mine = (l < 32);
            const unsigned int* fp = flags + (size_t)(wv * 32 + (l & 31)) * 16;
            for (;;) {
                unsigned v = mine ? ALD(fp) : tgt;
                if (__all(v >= tgt)) break;
                __builtin_amdgcn_s_sleep(1);
            }
        }

        const unsigned long long* hh8 =
            (const unsigned long long*)(hth + (size_t)(t & 1) * 65536);
        const unsigned long long* hl8 =
            (const unsigned long long*)(htl + (size_t)(t & 1) * 65536);

        // recurrent term: fragment-order planes, atomic u64 LLC loads, no unpack
        AH_IT(0); AH_IT(1); AH_IT(2); AH_IT(3);
        AH_IT(4); AH_IT(5); AH_IT(6); AH_IT(7);

        // cross-wave K reduction
        red[wv][0][0][l] = acc00; red[wv][0][1][l] = acc01;
        red[wv][1][0][l] = acc10; red[wv][1][1][l] = acc11;
        __syncthreads();
        #pragma unroll
        for (int o = tid; o < 1024; o += NTHR) {
            int f = o >> 9, m = (o >> 8) & 1, l2 = (o >> 2) & 63, r = o & 3;
            float s = 0.f;
            #pragma unroll
            for (int w = 0; w < 8; ++w) s += red[w][f][m][l2][r];
            int b = 16 * m + 4 * (l2 >> 4) + r;
            int c = l2 & 15;
            int gate = 2 * f + (c >> 3), jl = c & 7;
            gbuf[gate][b][jl] = s + sgl[gate][b][jl];
        }
        __syncthreads();

        // activation: 128 threads, each owns cells (ab, jb+ajp) and (ab, jb+ajp+1)
        if (tid < 128) {
            unsigned short* hthn = hth + (size_t)((t & 1) ^ 1) * 65536;
            unsigned short* htln = htl + (size_t)((t & 1) ^ 1) * 65536;
            float iv0 = gbuf[0][ab][ajp],     fv0 = gbuf[1][ab][ajp];
            float gv0 = gbuf[2][ab][ajp],     ov0 = gbuf[3][ab][ajp];
            float iv1 = gbuf[0][ab][ajp + 1], fv1 = gbuf[1][ab][ajp + 1];
            float gv1 = gbuf[2][ab][ajp + 1], ov1 = gbuf[3][ab][ajp + 1];
            float cn0 = sigf(fv0) * creg0 + sigf(iv0) * tanhf(gv0);
            float cn1 = sigf(fv1) * creg1 + sigf(iv1) * tanhf(gv1);
            float hn0 = sigf(ov0) * tanhf(cn0);
            float hn1 = sigf(ov1) * tanhf(cn1);
            creg0 = cn0; creg1 = cn1;
            int j0 = jb + ajp;
            unsigned short h0h = f2bf(hn0), h1h = f2bf(hn1);
            unsigned short h0l = f2bf(hn0 - bf2f(h0h));
            unsigned short h1l = f2bf(hn1 - bf2f(h1h));
            int T = j0 >> 5, lgp = (j0 & 15) >> 2, o = (j0 & 3) + 4 * ((j0 & 31) >> 4);
            int u32i = ((T * 4 + lgp) * 32 + ab) * 4 + (o >> 1);
            __hip_atomic_store((unsigned*)hthn + u32i,
                               (unsigned)h0h | ((unsigned)h1h << 16),
                               __ATOMIC_RELAXED, __HIP_MEMORY_SCOPE_AGENT);
            __hip_atomic_store((unsigned*)htln + u32i,
                               (unsigned)h0l | ((unsigned)h1l << 16),
                               __ATOMIC_RELAXED, __HIP_MEMORY_SCOPE_AGENT);
            float2 o2; o2.x = hn0; o2.y = hn1;
            *(float2*)(out + (size_t)t * HB + ab * H_DIM + j0) = o2;
        }

        // arrive: drain write-through stores to LLC, then one flag store
        if (t < T_DIM - 1) {
            asm volatile("s_waitcnt vmcnt(0)" ::: "memory");
            __syncthreads();
            if (tid == 0)
                __hip_atomic_store(flags + (size_t)blockIdx.x * 16,
                                   (unsigned)(t + 1), __ATOMIC_RELAXED,
                                   __HIP_MEMORY_SCOPE_AGENT);
        }
    }
}

extern "C" void kernel_launch(void* const* d_in, const int* in_sizes, int n_in,
                              void* d_out, int out_size, void* d_ws, size_t ws_size,
                              hipStream_t stream) {
    const float* embed    = (const float*)d_in[0];
    const float* enc_outs = (const float*)d_in[1];
    const float* h0       = (const float*)d_in[2];
    const float* c0       = (const float*)d_in[3];
    const float* W_ih     = (const float*)d_in[4];
    const float* W_hh     = (const float*)d_in[5];
    const float* b_ih     = (const float*)d_in[6];
    const float* b_hh     = (const float*)d_in[7];
    const int*   tok      = (const int*)d_in[8];
    const int*   langs    = (const int*)d_in[9];
    float* out = (float*)d_out;

    char* ws = (char*)d_ws;
    unsigned short* xh  = (unsigned short*)(ws + 0);
    unsigned short* xl  = (unsigned short*)(ws + 4194304);
    unsigned short* hth = (unsigned short*)(ws + 8388608);
    unsigned short* htl = (unsigned short*)(ws + 8650752);
    float*          si  = (float*)(ws + 8912896);
    unsigned int* flags = (unsigned int*)(ws + 9109504);

    hipLaunchKernelGGL(k_prep, dim3(512), dim3(256), 0, stream,
                       enc_outs, embed, langs, h0, si, hth, htl, flags);
    hipLaunchKernelGGL(k_gather_x, dim3(T_DIM * B_DIM), dim3(128), 0, stream,
                       embed, tok, xh, xl);
    hipLaunchKernelGGL(k_lstm, dim3(NBLK), dim3(NTHR), 0, stream,
                       xh, xl, hth, htl, si, W_ih, W_hh, b_ih, b_hh, c0,
                       out, flags);
}

// Round 10
// 1028.401 us; speedup vs baseline: 2.6222x; 1.2839x over previous
//
#include <hip/hip_runtime.h>
#include <math.h>

// ---------------- problem dims ----------------
#define E_DIM 512     // embedding dim
#define H_DIM 2048    // hidden
#define G_DIM 8192    // 4*H
#define B_DIM 32      // batch
#define T_DIM 128     // target time
#define S_DIM 128     // source time
#define ENC2  1024    // 2*encoder_hidden
#define SI_DIM 1536   // E + 2*enc (static input)

#define NBLK 256      // persistent blocks (1 per CU)
#define NTHR 512      // 8 waves
#define JT   8        // hidden cols per block
#define KHW  (H_DIM/8)   // 256: W_hh K-slice per wave (8 tiles of 32)
#define KXW  (E_DIM/8)   // 64:  W_ih K-slice per wave (2 tiles of 32)
#define HB   (B_DIM*H_DIM)
#define HPLANE 65536     // ushorts per h plane buffer (64 tiles * 4 * 32 * 8)

// fragment-order plane layout: [tile(32k)][lg(4)][b(32)][8 ushorts]

// ---------------- workspace layout (bytes) ----------------
// xh    ushort [128][16384]  @ 0         (4194304)
// xl    ushort [128][16384]  @ 4194304   (4194304)
// hth   ushort [129][65536]  @ 8388608   (16908288)  rotating per-step buffers
// htl   ushort [129][65536]  @ 25296896  (16908288)
// si    f32 [32][1536]       @ 42205184  (196608)
// flags u32 [256]x16         @ 42401792  (16384)
// total ~42.4 MB

typedef __bf16 bf16_t;
typedef bf16_t bf16x8 __attribute__((ext_vector_type(8)));
typedef float f32x4 __attribute__((ext_vector_type(4)));
typedef unsigned int u32x4 __attribute__((ext_vector_type(4)));

__device__ __forceinline__ unsigned short f2bf(float x) {
    unsigned u = __float_as_uint(x);
    u += 0x7FFFu + ((u >> 16) & 1u);   // RNE
    return (unsigned short)(u >> 16);
}
__device__ __forceinline__ float bf2f(unsigned short s) {
    return __uint_as_float(((unsigned)s) << 16);
}
__device__ __forceinline__ unsigned pack2(float a, float b) {
    return (unsigned)f2bf(a) | ((unsigned)f2bf(b) << 16);
}
__device__ __forceinline__ f32x4 mfma16(bf16x8 a, bf16x8 b, f32x4 c) {
    return __builtin_amdgcn_mfma_f32_16x16x32_bf16(a, b, c, 0, 0, 0);
}
__device__ __forceinline__ bf16x8 tofrag(u32x4 q) {
    return __builtin_bit_cast(bf16x8, q);
}
__device__ __forceinline__ float sigf(float x) { return 1.f / (1.f + expf(-x)); }

#define OPAQUE(v) asm volatile("" : "+v"(v))
#define ALD(p) __hip_atomic_load((p), __ATOMIC_RELAXED, __HIP_MEMORY_SCOPE_AGENT)

// W packing: BY-VALUE return of two u32x4
struct WPair { u32x4 hi, lo; };
__device__ __forceinline__ WPair packW(const float* src) {
    float4 w0 = *(const float4*)src;
    float4 w1 = *(const float4*)(src + 16);
    u32x4 qh;
    qh.x = pack2(w0.x, w0.y); qh.y = pack2(w0.z, w0.w);
    qh.z = pack2(w1.x, w1.y); qh.w = pack2(w1.z, w1.w);
    float r0 = w0.x - bf2f((unsigned short)(qh.x & 0xFFFF));
    float r1 = w0.y - bf2f((unsigned short)(qh.x >> 16));
    float r2 = w0.z - bf2f((unsigned short)(qh.y & 0xFFFF));
    float r3 = w0.w - bf2f((unsigned short)(qh.y >> 16));
    float r4 = w1.x - bf2f((unsigned short)(qh.z & 0xFFFF));
    float r5 = w1.y - bf2f((unsigned short)(qh.z >> 16));
    float r6 = w1.z - bf2f((unsigned short)(qh.w & 0xFFFF));
    float r7 = w1.w - bf2f((unsigned short)(qh.w >> 16));
    u32x4 ql;
    ql.x = pack2(r0, r1); ql.y = pack2(r2, r3);
    ql.z = pack2(r4, r5); ql.w = pack2(r6, r7);
    WPair out; out.hi = qh; out.lo = ql;
    return out;
}

// ---- prep: context max-pool, lang embed, h0 -> fragment-order planes (buf 0) ----
__global__ void k_prep(const float* __restrict__ enc_outs, const float* __restrict__ embed,
                       const int* __restrict__ langs, const float* __restrict__ h0,
                       float* __restrict__ si, unsigned short* __restrict__ hth,
                       unsigned short* __restrict__ htl, unsigned int* __restrict__ flags) {
    int tid = blockIdx.x * blockDim.x + threadIdx.x;
    int np = gridDim.x * blockDim.x;
    for (int i = tid; i < NBLK * 16; i += np)
        flags[i] = 0u;
    for (int i = tid; i < B_DIM * ENC2; i += np) {        // context = max over S
        int b = i >> 10, e = i & 1023;
        float m = -3.4e38f;
        for (int s = 0; s < S_DIM; ++s)
            m = fmaxf(m, enc_outs[(s * B_DIM + b) * ENC2 + e]);
        si[b * SI_DIM + E_DIM + e] = m;
    }
    for (int i = tid; i < B_DIM * E_DIM; i += np) {       // lang embedding
        int b = i >> 9, e = i & 511;
        si[b * SI_DIM + e] = embed[(long)langs[b] * E_DIM + e];
    }
    for (int i = tid; i < B_DIM * H_DIM; i += np) {       // h0 into buffer 0
        int b = i >> 11, j = i & 2047;
        float h = h0[i];
        unsigned short hi = f2bf(h);
        unsigned short lo = f2bf(h - bf2f(hi));
        int T = j >> 5, lgp = (j & 15) >> 2, o = (j & 3) + 4 * ((j & 31) >> 4);
        int idx = ((T * 4 + lgp) * 32 + b) * 8 + o;
        hth[idx] = hi;
        htl[idx] = lo;
    }
}

// ---- gather token embeddings -> fragment-order x planes; block r = t*32+b ----
__global__ void k_gather_x(const float* __restrict__ embed, const int* __restrict__ tok,
                           unsigned short* __restrict__ xh, unsigned short* __restrict__ xl) {
    int r = blockIdx.x;
    int t = r >> 5, b = r & 31;
    long row = tok[b * T_DIM + t];
    const float4* src = (const float4*)(embed + row * E_DIM);
    unsigned* xhp = (unsigned*)(xh + (size_t)t * 16384);
    unsigned* xlp = (unsigned*)(xl + (size_t)t * 16384);
    for (int g = threadIdx.x; g < 128; g += blockDim.x) {
        float4 v = src[g];
        unsigned h01 = pack2(v.x, v.y), h23 = pack2(v.z, v.w);
        float rx = v.x - bf2f((unsigned short)(h01 & 0xFFFF));
        float ry = v.y - bf2f((unsigned short)(h01 >> 16));
        float rz = v.z - bf2f((unsigned short)(h23 & 0xFFFF));
        float rw = v.w - bf2f((unsigned short)(h23 >> 16));
        int T = g >> 3, lgp = g & 3, o0 = 4 * ((g & 7) >> 2);
        int u32i = ((T * 4 + lgp) * 32 + b) * 4 + (o0 >> 1);
        uint2 qh; qh.x = h01; qh.y = h23;
        uint2 ql; ql.x = pack2(rx, ry); ql.y = pack2(rz, rw);
        *(uint2*)(xhp + u32i) = qh;
        *(uint2*)(xlp + u32i) = ql;
    }
}

// 12 MFMAs of one 32-k tile against fragment set PFX{h,l}{0,1}IT
#define MFMA12(PH, PL, IT) \
    acc00 = mfma16(Ah0, tofrag(PH##0##IT), acc00); \
    acc00 = mfma16(Ah0, tofrag(PL##0##IT), acc00); \
    acc00 = mfma16(Al0, tofrag(PH##0##IT), acc00); \
    acc01 = mfma16(Ah1, tofrag(PH##0##IT), acc01); \
    acc01 = mfma16(Ah1, tofrag(PL##0##IT), acc01); \
    acc01 = mfma16(Al1, tofrag(PH##0##IT), acc01); \
    acc10 = mfma16(Ah0, tofrag(PH##1##IT), acc10); \
    acc10 = mfma16(Ah0, tofrag(PL##1##IT), acc10); \
    acc10 = mfma16(Al0, tofrag(PH##1##IT), acc10); \
    acc11 = mfma16(Ah1, tofrag(PH##1##IT), acc11); \
    acc11 = mfma16(Ah1, tofrag(PL##1##IT), acc11); \
    acc11 = mfma16(Al1, tofrag(PH##1##IT), acc11);

// x tile: cached uint4 loads, fragment-contiguous, zero unpack
#define AX_IT(IT) do { \
    const int fb = ((wv * 2 + (IT)) * 4 + lg) * 32 + lr; \
    bf16x8 Ah0 = __builtin_bit_cast(bf16x8, xh4[fb]); \
    bf16x8 Ah1 = __builtin_bit_cast(bf16x8, xh4[fb + 16]); \
    bf16x8 Al0 = __builtin_bit_cast(bf16x8, xl4[fb]); \
    bf16x8 Al1 = __builtin_bit_cast(bf16x8, xl4[fb + 16]); \
    MFMA12(Xh, Xl, IT) \
} while (0)

// h tile: cached uint4 loads from this step's FRESH buffer (rotating buffers:
// addresses never cached before this step -> L2 can't be stale, XCD blocks share)
#define AH_IT(IT) do { \
    const int fb = ((wv * 8 + (IT)) * 4 + lg) * 32 + lr; \
    bf16x8 Ah0 = __builtin_bit_cast(bf16x8, hh4[fb]); \
    bf16x8 Ah1 = __builtin_bit_cast(bf16x8, hh4[fb + 16]); \
    bf16x8 Al0 = __builtin_bit_cast(bf16x8, hl4[fb]); \
    bf16x8 Al1 = __builtin_bit_cast(bf16x8, hl4[fb + 16]); \
    MFMA12(Wh, Wl, IT) \
} while (0)

#define PK_HH(F, IT) { WPair p = packW(W_hh + (long)rowf##F * H_DIM + (wv * KHW + IT * 32 + 4 * lg)); \
                       Wh##F##IT = p.hi; Wl##F##IT = p.lo; }
#define PK_X(F, IT)  { WPair p = packW(W_ih + (long)rowf##F * 2048 + (wv * KXW + IT * 32 + 4 * lg)); \
                       Xh##F##IT = p.hi; Xl##F##IT = p.lo; }

// ---- persistent LSTM: W in registers, rotating h buffers, per-wave wait ----
__global__ __launch_bounds__(NTHR, 2) void k_lstm(
        const unsigned short* __restrict__ xh, const unsigned short* __restrict__ xl,
        unsigned short* __restrict__ hth, unsigned short* __restrict__ htl,
        const float* __restrict__ si, const float* __restrict__ W_ih,
        const float* __restrict__ W_hh, const float* __restrict__ b_ih,
        const float* __restrict__ b_hh, const float* __restrict__ c0,
        float* __restrict__ out, unsigned int* __restrict__ flags) {
    __shared__ f32x4 red[8][2][2][64];     // [wave][frag][Ahalf][lane] partials (32 KB)
    __shared__ float gbuf[4][B_DIM][JT];   // gates (4 KB)
    __shared__ float sgl[4][B_DIM][JT];    // static gate bias (4 KB)

    const int tid = threadIdx.x;
    const int wv = tid >> 6, l = tid & 63, lr = l & 15, lg = l >> 4;
    const int jb = blockIdx.x * JT;

    // ---- prologue 1: static gate bias sg (fp32, block-local) ----
    {
        int c = tid >> 4, bp = tid & 15;
        int gate = c >> 3, jl = c & 7;
        long grow = (long)(gate * H_DIM + jb + jl);
        const float* wrow = W_ih + grow * 2048 + E_DIM;
        const float* s0 = si + bp * SI_DIM;
        const float* s1 = si + (bp + 16) * SI_DIM;
        float a0 = 0.f, a1 = 0.f;
        for (int k = 0; k < SI_DIM; k += 4) {
            float4 w  = *(const float4*)(wrow + k);
            float4 x0 = *(const float4*)(s0 + k);
            float4 x1 = *(const float4*)(s1 + k);
            a0 += w.x * x0.x + w.y * x0.y + w.z * x0.z + w.w * x0.w;
            a1 += w.x * x1.x + w.y * x1.y + w.z * x1.z + w.w * x1.w;
        }
        float bias = b_ih[grow] + b_hh[grow];
        sgl[gate][bp][jl] = a0 + bias;
        sgl[gate][bp + 16][jl] = a1 + bias;
    }

    // ---- prologue 2: W slices into NAMED register fragments, pinned ----
    const int rowf0 = ((lr >> 3)) * H_DIM + jb + (lr & 7);
    const int rowf1 = (2 + (lr >> 3)) * H_DIM + jb + (lr & 7);

    u32x4 Wh00, Wh01, Wh02, Wh03, Wh04, Wh05, Wh06, Wh07;
    u32x4 Wh10, Wh11, Wh12, Wh13, Wh14, Wh15, Wh16, Wh17;
    u32x4 Wl00, Wl01, Wl02, Wl03, Wl04, Wl05, Wl06, Wl07;
    u32x4 Wl10, Wl11, Wl12, Wl13, Wl14, Wl15, Wl16, Wl17;
    u32x4 Xh00, Xh01, Xh10, Xh11, Xl00, Xl01, Xl10, Xl11;

    PK_HH(0, 0) PK_HH(0, 1) PK_HH(0, 2) PK_HH(0, 3)
    PK_HH(0, 4) PK_HH(0, 5) PK_HH(0, 6) PK_HH(0, 7)
    PK_HH(1, 0) PK_HH(1, 1) PK_HH(1, 2) PK_HH(1, 3)
    PK_HH(1, 4) PK_HH(1, 5) PK_HH(1, 6) PK_HH(1, 7)
    PK_X(0, 0) PK_X(0, 1) PK_X(1, 0) PK_X(1, 1)

    OPAQUE(Wh00); OPAQUE(Wh01); OPAQUE(Wh02); OPAQUE(Wh03);
    OPAQUE(Wh04); OPAQUE(Wh05); OPAQUE(Wh06); OPAQUE(Wh07);
    OPAQUE(Wh10); OPAQUE(Wh11); OPAQUE(Wh12); OPAQUE(Wh13);
    OPAQUE(Wh14); OPAQUE(Wh15); OPAQUE(Wh16); OPAQUE(Wh17);
    OPAQUE(Wl00); OPAQUE(Wl01); OPAQUE(Wl02); OPAQUE(Wl03);
    OPAQUE(Wl04); OPAQUE(Wl05); OPAQUE(Wl06); OPAQUE(Wl07);
    OPAQUE(Wl10); OPAQUE(Wl11); OPAQUE(Wl12); OPAQUE(Wl13);
    OPAQUE(Wl14); OPAQUE(Wl15); OPAQUE(Wl16); OPAQUE(Wl17);
    OPAQUE(Xh00); OPAQUE(Xh01); OPAQUE(Xh10); OPAQUE(Xh11);
    OPAQUE(Xl00); OPAQUE(Xl01); OPAQUE(Xl10); OPAQUE(Xl11);

    // ---- prologue 3: cell state; 128 act threads own j-pairs ----
    const int ab = (tid & 127) >> 2, ajp = (tid & 3) * 2;   // b, j-pair base
    float creg0 = 0.f, creg1 = 0.f;
    if (tid < 128) {
        creg0 = c0[ab * H_DIM + jb + ajp];
        creg1 = c0[ab * H_DIM + jb + ajp + 1];
    }

    __syncthreads();   // sgl ready

    // ---- time loop ----
    #pragma unroll 1
    for (int t = 0; t < T_DIM; ++t) {
        f32x4 acc00 = {}, acc01 = {}, acc10 = {}, acc11 = {};  // [frag][Ahalf]

        // input term FIRST (cached, hot in L2 — no invalidates anywhere)
        {
            const uint4* xh4 = (const uint4*)(xh + (size_t)t * 16384);
            const uint4* xl4 = (const uint4*)(xl + (size_t)t * 16384);
            AX_IT(0); AX_IT(1);
        }

        // per-wave partial wait: wave wv needs h-units from blocks wv*32..wv*32+31
        if (t > 0) {
            const unsigned tgt = (unsigned)t;
            const bool mine = (l < 32);
            const unsigned int* fp = flags + (size_t)(wv * 32 + (l & 31)) * 16;
            for (;;) {
                unsigned v = mine ? ALD(fp) : tgt;
                if (__all(v >= tgt)) break;
                __builtin_amdgcn_s_sleep(1);
            }
            __builtin_amdgcn_sched_barrier(0);   // no h-load hoisting above wait
        }

        // recurrent term: cached uint4 loads from this step's fresh buffer;
        // 32 blocks per XCD share via L2 (first reader pulls from LLC)
        {
            const uint4* hh4 = (const uint4*)(hth + (size_t)t * HPLANE);
            const uint4* hl4 = (const uint4*)(htl + (size_t)t * HPLANE);
            AH_IT(0); AH_IT(1); AH_IT(2); AH_IT(3);
            AH_IT(4); AH_IT(5); AH_IT(6); AH_IT(7);
        }

        // cross-wave K reduction
        red[wv][0][0][l] = acc00; red[wv][0][1][l] = acc01;
        red[wv][1][0][l] = acc10; red[wv][1][1][l] = acc11;
        __syncthreads();
        #pragma unroll
        for (int o = tid; o < 1024; o += NTHR) {
            int f = o >> 9, m = (o >> 8) & 1, l2 = (o >> 2) & 63, r = o & 3;
            float s = 0.f;
            #pragma unroll
            for (int w = 0; w < 8; ++w) s += red[w][f][m][l2][r];
            int b = 16 * m + 4 * (l2 >> 4) + r;
            int c = l2 & 15;
            int gate = 2 * f + (c >> 3), jl = c & 7;
            gbuf[gate][b][jl] = s + sgl[gate][b][jl];
        }
        __syncthreads();

        // activation: 128 threads, each owns cells (ab, jb+ajp) and (ab, jb+ajp+1);
        // h published to buffer t+1 via write-through atomic stores
        if (tid < 128) {
            unsigned* hthn = (unsigned*)(hth + (size_t)(t + 1) * HPLANE);
            unsigned* htln = (unsigned*)(htl + (size_t)(t + 1) * HPLANE);
            float iv0 = gbuf[0][ab][ajp],     fv0 = gbuf[1][ab][ajp];
            float gv0 = gbuf[2][ab][ajp],     ov0 = gbuf[3][ab][ajp];
            float iv1 = gbuf[0][ab][ajp + 1], fv1 = gbuf[1][ab][ajp + 1];
            float gv1 = gbuf[2][ab][ajp + 1], ov1 = gbuf[3][ab][ajp + 1];
            float cn0 = sigf(fv0) * creg0 + sigf(iv0) * tanhf(gv0);
            float cn1 = sigf(fv1) * creg1 + sigf(iv1) * tanhf(gv1);
            float hn0 = sigf(ov0) * tanhf(cn0);
            float hn1 = sigf(ov1) * tanhf(cn1);
            creg0 = cn0; creg1 = cn1;
            int j0 = jb + ajp;
            unsigned short h0h = f2bf(hn0), h1h = f2bf(hn1);
            unsigned short h0l = f2bf(hn0 - bf2f(h0h));
            unsigned short h1l = f2bf(hn1 - bf2f(h1h));
            int T = j0 >> 5, lgp = (j0 & 15) >> 2, o = (j0 & 3) + 4 * ((j0 & 31) >> 4);
            int u32i = ((T * 4 + lgp) * 32 + ab) * 4 + (o >> 1);
            __hip_atomic_store(hthn + u32i, (unsigned)h0h | ((unsigned)h1h << 16),
                               __ATOMIC_RELAXED, __HIP_MEMORY_SCOPE_AGENT);
            __hip_atomic_store(htln + u32i, (unsigned)h0l | ((unsigned)h1l << 16),
                               __ATOMIC_RELAXED, __HIP_MEMORY_SCOPE_AGENT);
            float2 o2; o2.x = hn0; o2.y = hn1;
            *(float2*)(out + (size_t)t * HB + ab * H_DIM + j0) = o2;
        }

        // arrive: drain write-through stores to LLC, then one flag store
        if (t < T_DIM - 1) {
            asm volatile("s_waitcnt vmcnt(0)" ::: "memory");
            __syncthreads();
            if (tid == 0)
                __hip_atomic_store(flags + (size_t)blockIdx.x * 16,
                                   (unsigned)(t + 1), __ATOMIC_RELAXED,
                                   __HIP_MEMORY_SCOPE_AGENT);
        }
    }
}

extern "C" void kernel_launch(void* const* d_in, const int* in_sizes, int n_in,
                              void* d_out, int out_size, void* d_ws, size_t ws_size,
                              hipStream_t stream) {
    const float* embed    = (const float*)d_in[0];
    const float* enc_outs = (const float*)d_in[1];
    const float* h0       = (const float*)d_in[2];
    const float* c0       = (const float*)d_in[3];
    const float* W_ih     = (const float*)d_in[4];
    const float* W_hh     = (const float*)d_in[5];
    const float* b_ih     = (const float*)d_in[6];
    const float* b_hh     = (const float*)d_in[7];
    const int*   tok      = (const int*)d_in[8];
    const int*   langs    = (const int*)d_in[9];
    float* out = (float*)d_out;

    char* ws = (char*)d_ws;
    unsigned short* xh  = (unsigned short*)(ws + 0);
    unsigned short* xl  = (unsigned short*)(ws + 4194304);
    unsigned short* hth = (unsigned short*)(ws + 8388608);
    unsigned short* htl = (unsigned short*)(ws + 25296896);
    float*          si  = (float*)(ws + 42205184);
    unsigned int* flags = (unsigned int*)(ws + 42401792);

    hipLaunchKernelGGL(k_prep, dim3(512), dim3(256), 0, stream,
                       enc_outs, embed, langs, h0, si, hth, htl, flags);
    hipLaunchKernelGGL(k_gather_x, dim3(T_DIM * B_DIM), dim3(128), 0, stream,
                       embed, tok, xh, xl);
    hipLaunchKernelGGL(k_lstm, dim3(NBLK), dim3(NTHR), 0, stream,
                       xh, xl, hth, htl, si, W_ih, W_hh, b_ih, b_hh, c0,
                       out, flags);
}